// Round 9
// baseline (127.194 us; speedup 1.0000x reference)
//
#include <hip/hip_runtime.h>
#include <hip/hip_cooperative_groups.h>
#include <math.h>

// Problem constants (from reference / setup_inputs)
#define N_ROIS   32
#define N_CAT    (N_ROIS * 9)      // 288 cat_rois rows
#define C_FEAT   256
#define H_FEAT   40
#define W_FEAT   40
#define P_FEAT   (H_FEAT * W_FEAT) // 1600 pixels
#define PH       7
#define PW       7
#define SCALE    0.0625f
#define MIN_SIZE 16.0f
#define CELLS    (PH * PW)                 // 49
#define POOL_PER_BOX (C_FEAT * CELLS)      // 12544
#define OUT_POOL_ELEMS ((size_t)N_CAT * POOL_PER_BOX)  // 3,612,672

#define N_TRANS_BLOCKS (P_FEAT / 32 * (C_FEAT / 32))   // 50*8 = 400

// pool unit = (box, channel-quarter)
#define CH_G     64                         // channels per unit
#define NCHG     4
#define NUNIT    (N_CAT * NCHG)             // 1152 units
#define NBLK8    1152                       // (v8 fallback grid)
#define TPB      448                        // 64 ch x 7 pooled rows = 7 waves
#define WROWS    14                         // max window rows (bsh <= 2)
#define WCOLS    14                         // window x-span kept static at 14
#define PIX      (WROWS * WCOLS)            // 196
#define SLOTS    (PIX + 2)                  // +2 px slack for guarded over-reads
#define WIN_FLTS (SLOTS * CH_G)             // 12,672 floats = 50,688 B
#define OBUF_FLTS (CH_G * CELLS)            // 3136 floats (overlays win)
#define QPP      (CH_G / 4)                 // 16 float4-quads per pixel

#define CBLK     384                        // coop grid (<= pessimistic 512 cap)

// ===========================================================================
// v9 cooperative kernel: transpose + anchors | grid.sync | full-line pool.
// Evidence: v7 (single launch) fits the 6cy/line model at 22us; v8 split the
// transpose into a 2nd launch and LOST the full-line gain to a ~10us
// inter-launch gap (graded 79.6 vs predicted 69). So: same-dispatch phases.
// Phase 2 = v8's passed pool body + y-trimmed stage (stage WH<=14 real rows,
// avg ~9.5 -> ~530 stage lines + 196 drain lines per unit) + ticket-balanced
// unit scheduling. ft (1.6MB) fits every XCD L2 -> no swizzle needed.
// ===========================================================================
__global__ __launch_bounds__(TPB, 4) void
coop_v9(const float* __restrict__ f,
        const float* __restrict__ rois,
        const int* __restrict__ hh_p,
        const int* __restrict__ hw_p,
        float* __restrict__ out,
        float* __restrict__ ft) {
    __shared__ __align__(16) float win[WIN_FLTS];   // 50,688 B
    __shared__ unsigned su;

    const int bid = blockIdx.x;
    const int tid = threadIdx.x;
    unsigned* ctr = (unsigned*)(ft + (size_t)C_FEAT * P_FEAT);
    float* cat_out = out + OUT_POOL_ELEMS;

    if (bid == 0 && tid == 0) atomicExch(ctr, 0u);   // visible after grid sync

    // ---------------- phase 1a: transpose tiles (proven 32x32 LDS tile) ----
    // tiles 0..383 -> block bid; tiles 384..399 -> blocks 0..15 (2nd pass).
    float (*tile)[33] = (float(*)[33])win;           // 32*33*4 = 4224 B of win
    #pragma unroll
    for (int pass = 0; pass < 2; ++pass) {
        const int tno = bid + pass * CBLK;
        const bool act = (tno < N_TRANS_BLOCKS) && (pass == 0 || bid < N_TRANS_BLOCKS - CBLK);
        if (!act) continue;                          // block-uniform
        const int pt = (tno % (P_FEAT / 32)) * 32;
        const int ct = (tno / (P_FEAT / 32)) * 32;
        const int lx = tid & 31;
        const int ly = (tid >> 5) & 7;               // 0..7 (threads 256..447 dup row range)
        if (tid < 256) {
            #pragma unroll
            for (int ii = 0; ii < 32; ii += 8)
                tile[ly + ii][lx] = f[(ct + ly + ii) * P_FEAT + (pt + lx)];
        }
        __syncthreads();
        if (tid < 256) {
            #pragma unroll
            for (int ii = 0; ii < 32; ii += 8)
                ft[(pt + ly + ii) * C_FEAT + (ct + lx)] = tile[lx][ly + ii];
        }
        __syncthreads();                             // win free for next pass
    }

    // ---------------- phase 1b: context anchors + IoU (verbatim; PASSED) ----
    if (bid == CBLK - 1) {                           // block-uniform
        float* R = win;                              // 160 floats of win
        if (tid < N_ROIS * 5) R[tid] = rois[tid];
        __syncthreads();
        if (tid < 256) {
            const float hh = (float)(*hh_p);
            const float hw = (float)(*hw_p);
            const int g = tid;
            const int n = g >> 3;
            const int j = g & 7;
            const int m = (j < 4) ? j : j + 1;       // skip center of 3x3
            const int r  = m / 3;
            const int cc = m % 3;

            const float x1 = R[n * 5 + 1], y1 = R[n * 5 + 2];
            const float x2 = R[n * 5 + 3], y2 = R[n * 5 + 4];
            const float w = x2 - x1, h = y2 - y1;

            const float cx = x1 + w * ((float)cc - 0.5f);
            const float cy = y1 + h * ((float)r  - 0.5f);
            float bx1 = cx - w * 0.25f;
            float by1 = cy - h * 0.25f;
            float bx2 = cx + w * 0.25f;
            float by2 = cy + h * 0.25f;
            const float bw = bx2 - bx1 + 1.0f;
            const float bh = by2 - by1 + 1.0f;
            const bool invalid = (bx1 < 0.0f) || (by1 < 0.0f) ||
                                 (bx2 >= hw) || (by2 >= hh) ||
                                 (bw < MIN_SIZE) || (bh < MIN_SIZE);
            if (invalid) { bx1 = x1; by1 = y1; bx2 = x2; by2 = y2; }

            const float gw = bx2 - bx1 + 1.0f;
            const float gh = by2 - by1 + 1.0f;
            const float garea = gw * gh;
            const bool gdeg = (gw == 1.0f) && (gh == 1.0f);

            float best_ov = -INFINITY;
            int best = 0;
            for (int a = 0; a < N_ROIS; ++a) {
                const float ax1 = R[a * 5 + 1], ay1 = R[a * 5 + 2];
                const float ax2 = R[a * 5 + 3], ay2 = R[a * 5 + 4];
                const float aw = ax2 - ax1 + 1.0f, ah = ay2 - ay1 + 1.0f;
                float iw = fminf(ax2, bx2) - fmaxf(ax1, bx1) + 1.0f;
                float ih = fminf(ay2, by2) - fmaxf(ay1, by1) + 1.0f;
                iw = fmaxf(iw, 0.0f);
                ih = fmaxf(ih, 0.0f);
                const float inter = iw * ih;
                float ov = inter / (aw * ah + garea - inter);
                if (gdeg) ov = 0.0f;
                if (aw == 1.0f && ah == 1.0f) ov = -1.0f;
                if (ov > best_ov) { best_ov = ov; best = a; }
            }

            bool label = (best_ov >= 0.3f);
            const float w_cell = bx2 - bx1;
            const float h_cell = by2 - by1;
            const float rw = label ? (R[best * 5 + 3] - R[best * 5 + 1]) : 0.0f;
            const float rh = label ? (R[best * 5 + 4] - R[best * 5 + 2]) : 0.0f;
            label = label &&
                    !(fmaxf(rw, rh) >= fmaxf(w_cell, h_cell)) &&
                    !(fminf(rw, rh) < fminf(w_cell, h_cell) / 3.0f);
            if (label) {
                bx1 = R[best * 5 + 1]; by1 = R[best * 5 + 2];
                bx2 = R[best * 5 + 3]; by2 = R[best * 5 + 4];
            }

            float* row = cat_out + (size_t)(n * 9 + 1 + j) * 5;
            row[0] = 0.0f;
            row[1] = bx1; row[2] = by1; row[3] = bx2; row[4] = by2;
            if (j == 0) {
                float* rr = cat_out + (size_t)(n * 9) * 5;
                #pragma unroll
                for (int t = 0; t < 5; ++t) rr[t] = R[n * 5 + t];
            }
        }
        __syncthreads();
    }

    // ---------------- grid-wide sync: ft + cat_rois + ctr visible ----------
    cooperative_groups::this_grid().sync();

    // ---------------- phase 2: ticket-scheduled full-line pool units -------
    const int cl = tid & 63;          // local channel 0..63
    const int i  = tid >> 6;          // pooled row 0..6 (wave-uniform)

    for (;;) {
        if (tid == 0) su = atomicAdd(ctr, 1u);
        __syncthreads();
        const unsigned u = su;
        if (u >= (unsigned)NUNIT) break;          // uniform exit

        const int b  = (int)(u >> 2);             // box 0..287
        const int cg = (int)(u & 3);              // channel quarter

        const float* cr = cat_out + (size_t)b * 5;
        const float bx1 = cr[1], by1 = cr[2], bx2 = cr[3], by2 = cr[4];
        // jnp.round = round-half-to-even = rintf (default rounding mode)
        const float sw = rintf(bx1 * SCALE);
        const float sh = rintf(by1 * SCALE);
        const float ew = rintf(bx2 * SCALE);
        const float eh = rintf(by2 * SCALE);
        const float bsh = fmaxf(eh - sh + 1.0f, 1.0f) * (1.0f / (float)PH);
        const float bsw = fmaxf(ew - sw + 1.0f, 1.0f) * (1.0f / (float)PW);

        const int hs = __builtin_amdgcn_readfirstlane(
            (int)fminf(fmaxf(floorf((float)i * bsh) + sh, 0.0f), (float)H_FEAT));
        const int he = __builtin_amdgcn_readfirstlane(
            (int)fminf(fmaxf(ceilf((float)(i + 1) * bsh) + sh, 0.0f), (float)H_FEAT));

        int ws[PW], we[PW];
        #pragma unroll
        for (int j = 0; j < PW; ++j) {
            ws[j] = __builtin_amdgcn_readfirstlane(
                (int)fminf(fmaxf(floorf((float)j * bsw) + sw, 0.0f), (float)W_FEAT));
            we[j] = __builtin_amdgcn_readfirstlane(
                (int)fminf(fmaxf(ceilf((float)(j + 1) * bsw) + sw, 0.0f), (float)W_FEAT));
        }
        const int xs = ws[0];
        const int ys = __builtin_amdgcn_readfirstlane(
            (int)fminf(fmaxf(sh, 0.0f), (float)H_FEAT));
        const int yend = __builtin_amdgcn_readfirstlane(
            (int)fminf(fmaxf(ceilf((float)PH * bsh) + sh, 0.0f), (float)H_FEAT));
        const int WH = yend - ys;                 // 0..14 actual window rows

        const bool narrow = (bsw <= 2.0f) && (bsh <= 2.0f);   // block-uniform
        const bool rowv = (he > hs);

        if (narrow) {
            // ---- stage: WH x 14 px x 64ch, pixel-major ft -> LDS ----
            // only real rows staged (avg WH~9.5 -> ~530 full lines/unit)
            const float* fb = ft + cg * CH_G;
            const int nq4 = WH * WCOLS * QPP;     // uniform trip count
            for (int e = tid; e < nq4; e += TPB) {
                const int q = e & (QPP - 1);      // quad 0..15
                const int p = e >> 4;             // pixel 0..WH*14-1
                const int py = p / WCOLS;         // const-div magic
                const int px = p - py * WCOLS;
                const int gy = (ys + py < H_FEAT - 1) ? (ys + py) : (H_FEAT - 1);
                const int gx = (xs + px < W_FEAT - 1) ? (xs + px) : (W_FEAT - 1);
                // clamped slots are never consumed (guards below)
                const float4 v = *(const float4*)(fb + ((size_t)(gy * W_FEAT + gx)
                                                        << 8) + (q << 2));
                *(float4*)(win + p * CH_G + q * 4) = v;
            }
            __syncthreads();

            // ---- compute: per cell <=3 batched ds_reads + uniform guards ----
            float mx[PW];
            #pragma unroll
            for (int j = 0; j < PW; ++j) mx[j] = -1e30f;

            int off[PW], nj[PW];
            #pragma unroll
            for (int j = 0; j < PW; ++j) {
                off[j] = ws[j] - xs;             // 0..12 (SGPR)
                nj[j]  = we[j] - ws[j];          // 0..3  (SGPR)
            }
            for (int y = hs; y < he; ++y) {
                const float* wr = win + (y - ys) * (WCOLS * CH_G) + cl;
                #pragma unroll
                for (int j = 0; j < PW; ++j) {
                    // over-reads land in slack / stale rows: guarded, unused
                    const float* p0 = wr + off[j] * CH_G;
                    const float d0 = p0[0];
                    const float d1 = p0[CH_G];
                    const float d2 = p0[2 * CH_G];
                    if (nj[j] > 0) mx[j] = fmaxf(mx[j], d0);
                    if (nj[j] > 1) mx[j] = fmaxf(mx[j], d1);
                    if (nj[j] > 2) mx[j] = fmaxf(mx[j], d2);
                }
            }
            __syncthreads();    // all win reads done -> overlay obuf

            // ---- obuf (overlays win): stride 49 (odd: conflict-free) ----
            float* orow = win + cl * CELLS + i * PW;
            #pragma unroll
            for (int j = 0; j < PW; ++j)
                orow[j] = (rowv && (nj[j] > 0)) ? mx[j] : 0.0f;
            __syncthreads();

            // ---- dense drain: 784 float4 -> contiguous 196-line slice ----
            const float4* src = (const float4*)win;
            float4* dst = (float4*)(out + (size_t)b * POOL_PER_BOX
                                        + (size_t)cg * OBUF_FLTS);
            dst[tid] = src[tid];
            const int e2 = tid + TPB;
            if (e2 < OBUF_FLTS / 4) dst[e2] = src[e2];
        } else {
            // general fallback (not taken for this data)
            const int c = cg * CH_G + cl;
            float mx[PW];
            #pragma unroll
            for (int j = 0; j < PW; ++j) mx[j] = -1e30f;
            for (int y = hs; y < he; ++y) {
                #pragma unroll
                for (int j = 0; j < PW; ++j)
                    for (int x = ws[j]; x < we[j]; ++x)
                        mx[j] = fmaxf(mx[j], ft[(size_t)(y * W_FEAT + x) * C_FEAT + c]);
            }
            float* ob = out + (size_t)b * POOL_PER_BOX + (size_t)c * CELLS + i * PW;
            #pragma unroll
            for (int j = 0; j < PW; ++j)
                ob[j] = (rowv && (we[j] > ws[j])) ? mx[j] : 0.0f;
        }
        __syncthreads();        // win + su free for next ticket
    }
}

// ===========================================================================
// Fallback path (v8, PASSED): used only if cooperative launch unavailable.
// ===========================================================================
__global__ void prep_kernel(const float* __restrict__ f,
                            const float* __restrict__ rois,
                            const int* __restrict__ hh_p,
                            const int* __restrict__ hw_p,
                            float* __restrict__ ft,
                            float* __restrict__ cat_out,
                            int use_transpose) {
    __shared__ float tile[32][33];
    __shared__ float R[N_ROIS * 5];
    const int bid = blockIdx.x;
    const int tid = threadIdx.x;

    if (bid < N_TRANS_BLOCKS) {
        if (!use_transpose) return;
        const int pt = (bid % (P_FEAT / 32)) * 32;
        const int ct = (bid / (P_FEAT / 32)) * 32;
        const int lx = tid & 31;
        const int ly = tid >> 5;
        #pragma unroll
        for (int i = 0; i < 32; i += 8)
            tile[ly + i][lx] = f[(ct + ly + i) * P_FEAT + (pt + lx)];
        __syncthreads();
        #pragma unroll
        for (int i = 0; i < 32; i += 8)
            ft[(pt + ly + i) * C_FEAT + (ct + lx)] = tile[lx][ly + i];
        return;
    }

    if (tid < N_ROIS * 5) R[tid] = rois[tid];
    __syncthreads();

    const float hh = (float)(*hh_p);
    const float hw = (float)(*hw_p);
    const int g = tid;
    const int n = g >> 3;
    const int j = g & 7;
    const int m = (j < 4) ? j : j + 1;
    const int r  = m / 3;
    const int cc = m % 3;

    const float x1 = R[n * 5 + 1], y1 = R[n * 5 + 2];
    const float x2 = R[n * 5 + 3], y2 = R[n * 5 + 4];
    const float w = x2 - x1, h = y2 - y1;

    const float cx = x1 + w * ((float)cc - 0.5f);
    const float cy = y1 + h * ((float)r  - 0.5f);
    float bx1 = cx - w * 0.25f;
    float by1 = cy - h * 0.25f;
    float bx2 = cx + w * 0.25f;
    float by2 = cy + h * 0.25f;
    const float bw = bx2 - bx1 + 1.0f;
    const float bh = by2 - by1 + 1.0f;
    const bool invalid = (bx1 < 0.0f) || (by1 < 0.0f) ||
                         (bx2 >= hw) || (by2 >= hh) ||
                         (bw < MIN_SIZE) || (bh < MIN_SIZE);
    if (invalid) { bx1 = x1; by1 = y1; bx2 = x2; by2 = y2; }

    const float gw = bx2 - bx1 + 1.0f;
    const float gh = by2 - by1 + 1.0f;
    const float garea = gw * gh;
    const bool gdeg = (gw == 1.0f) && (gh == 1.0f);

    float best_ov = -INFINITY;
    int best = 0;
    for (int a = 0; a < N_ROIS; ++a) {
        const float ax1 = R[a * 5 + 1], ay1 = R[a * 5 + 2];
        const float ax2 = R[a * 5 + 3], ay2 = R[a * 5 + 4];
        const float aw = ax2 - ax1 + 1.0f, ah = ay2 - ay1 + 1.0f;
        float iw = fminf(ax2, bx2) - fmaxf(ax1, bx1) + 1.0f;
        float ih = fminf(ay2, by2) - fmaxf(ay1, by1) + 1.0f;
        iw = fmaxf(iw, 0.0f);
        ih = fmaxf(ih, 0.0f);
        const float inter = iw * ih;
        float ov = inter / (aw * ah + garea - inter);
        if (gdeg) ov = 0.0f;
        if (aw == 1.0f && ah == 1.0f) ov = -1.0f;
        if (ov > best_ov) { best_ov = ov; best = a; }
    }

    bool label = (best_ov >= 0.3f);
    const float w_cell = bx2 - bx1;
    const float h_cell = by2 - by1;
    const float rw = label ? (R[best * 5 + 3] - R[best * 5 + 1]) : 0.0f;
    const float rh = label ? (R[best * 5 + 4] - R[best * 5 + 2]) : 0.0f;
    label = label &&
            !(fmaxf(rw, rh) >= fmaxf(w_cell, h_cell)) &&
            !(fminf(rw, rh) < fminf(w_cell, h_cell) / 3.0f);
    if (label) {
        bx1 = R[best * 5 + 1]; by1 = R[best * 5 + 2];
        bx2 = R[best * 5 + 3]; by2 = R[best * 5 + 4];
    }

    float* row = cat_out + (size_t)(n * 9 + 1 + j) * 5;
    row[0] = 0.0f;
    row[1] = bx1; row[2] = by1; row[3] = bx2; row[4] = by2;
    if (j == 0) {
        float* rr = cat_out + (size_t)(n * 9) * 5;
        #pragma unroll
        for (int t = 0; t < 5; ++t) rr[t] = R[n * 5 + t];
    }
}

__global__ __launch_bounds__(TPB) void
pool_v8(const float* __restrict__ ft,
        const float* __restrict__ cat_rois,
        float* __restrict__ out) {
    __shared__ __align__(16) float win[WIN_FLTS];

    const int s   = (blockIdx.x & 7) * (NBLK8 / 8) + (blockIdx.x >> 3);
    const int b   = s >> 2;
    const int cg  = s & 3;
    const int tid = threadIdx.x;
    const int cl  = tid & 63;
    const int i   = tid >> 6;

    const float* cr = cat_rois + (size_t)b * 5;
    const float bx1 = cr[1], by1 = cr[2], bx2 = cr[3], by2 = cr[4];
    const float sw = rintf(bx1 * SCALE);
    const float sh = rintf(by1 * SCALE);
    const float ew = rintf(bx2 * SCALE);
    const float eh = rintf(by2 * SCALE);
    const float bsh = fmaxf(eh - sh + 1.0f, 1.0f) * (1.0f / (float)PH);
    const float bsw = fmaxf(ew - sw + 1.0f, 1.0f) * (1.0f / (float)PW);

    const int hs = __builtin_amdgcn_readfirstlane(
        (int)fminf(fmaxf(floorf((float)i * bsh) + sh, 0.0f), (float)H_FEAT));
    const int he = __builtin_amdgcn_readfirstlane(
        (int)fminf(fmaxf(ceilf((float)(i + 1) * bsh) + sh, 0.0f), (float)H_FEAT));

    int ws[PW], we[PW];
    #pragma unroll
    for (int j = 0; j < PW; ++j) {
        ws[j] = __builtin_amdgcn_readfirstlane(
            (int)fminf(fmaxf(floorf((float)j * bsw) + sw, 0.0f), (float)W_FEAT));
        we[j] = __builtin_amdgcn_readfirstlane(
            (int)fminf(fmaxf(ceilf((float)(j + 1) * bsw) + sw, 0.0f), (float)W_FEAT));
    }
    const int xs = ws[0];
    const int ys = __builtin_amdgcn_readfirstlane(
        (int)fminf(fmaxf(sh, 0.0f), (float)H_FEAT));

    const bool narrow = (bsw <= 2.0f) && (bsh <= 2.0f);
    const bool rowv = (he > hs);

    if (narrow) {
        const float* fb = ft + cg * CH_G;
        #pragma unroll
        for (int t = 0; t < (PIX * QPP) / TPB; ++t) {
            const int e = tid + t * TPB;
            const int q = e & (QPP - 1);
            const int p = e >> 4;
            const int py = p / WCOLS;
            const int px = p - py * WCOLS;
            const int gy = (ys + py < H_FEAT - 1) ? (ys + py) : (H_FEAT - 1);
            const int gx = (xs + px < W_FEAT - 1) ? (xs + px) : (W_FEAT - 1);
            const float4 v = *(const float4*)(fb + ((size_t)(gy * W_FEAT + gx)
                                                    << 8) + (q << 2));
            *(float4*)(win + p * CH_G + q * 4) = v;
        }
        __syncthreads();

        float mx[PW];
        #pragma unroll
        for (int j = 0; j < PW; ++j) mx[j] = -1e30f;

        int off[PW], nj[PW];
        #pragma unroll
        for (int j = 0; j < PW; ++j) {
            off[j] = ws[j] - xs;
            nj[j]  = we[j] - ws[j];
        }
        for (int y = hs; y < he; ++y) {
            const float* wr = win + (y - ys) * (WCOLS * CH_G) + cl;
            #pragma unroll
            for (int j = 0; j < PW; ++j) {
                const float* p0 = wr + off[j] * CH_G;
                const float d0 = p0[0];
                const float d1 = p0[CH_G];
                const float d2 = p0[2 * CH_G];
                if (nj[j] > 0) mx[j] = fmaxf(mx[j], d0);
                if (nj[j] > 1) mx[j] = fmaxf(mx[j], d1);
                if (nj[j] > 2) mx[j] = fmaxf(mx[j], d2);
            }
        }
        __syncthreads();

        float* orow = win + cl * CELLS + i * PW;
        #pragma unroll
        for (int j = 0; j < PW; ++j)
            orow[j] = (rowv && (nj[j] > 0)) ? mx[j] : 0.0f;
        __syncthreads();

        const float4* src = (const float4*)win;
        float4* dst = (float4*)(out + (size_t)b * POOL_PER_BOX
                                    + (size_t)cg * OBUF_FLTS);
        dst[tid] = src[tid];
        const int e2 = tid + TPB;
        if (e2 < OBUF_FLTS / 4) dst[e2] = src[e2];
    } else {
        const int c = cg * CH_G + cl;
        float mx[PW];
        #pragma unroll
        for (int j = 0; j < PW; ++j) mx[j] = -1e30f;
        for (int y = hs; y < he; ++y) {
            #pragma unroll
            for (int j = 0; j < PW; ++j)
                for (int x = ws[j]; x < we[j]; ++x)
                    mx[j] = fmaxf(mx[j], ft[(size_t)(y * W_FEAT + x) * C_FEAT + c]);
        }
        float* ob = out + (size_t)b * POOL_PER_BOX + (size_t)c * CELLS + i * PW;
        #pragma unroll
        for (int j = 0; j < PW; ++j)
            ob[j] = (rowv && (we[j] > ws[j])) ? mx[j] : 0.0f;
    }
}

__global__ __launch_bounds__(256) void
roi_pool_kernel_nchw(const float* __restrict__ feat,
                     const float* __restrict__ cat_rois,
                     float* __restrict__ out) {
    const int i = blockIdx.x / N_CAT;
    const int b = blockIdx.x % N_CAT;
    const int c = threadIdx.x;

    const float* cr = cat_rois + (size_t)b * 5;
    const float sw = rintf(cr[1] * SCALE);
    const float sh = rintf(cr[2] * SCALE);
    const float ew = rintf(cr[3] * SCALE);
    const float eh = rintf(cr[4] * SCALE);
    const float bsh = fmaxf(eh - sh + 1.0f, 1.0f) * (1.0f / (float)PH);
    const float bsw = fmaxf(ew - sw + 1.0f, 1.0f) * (1.0f / (float)PW);

    const int hs = (int)fminf(fmaxf(floorf((float)i * bsh) + sh, 0.0f), (float)H_FEAT);
    const int he = (int)fminf(fmaxf(ceilf((float)(i + 1) * bsh) + sh, 0.0f), (float)H_FEAT);
    int ws[PW], we[PW];
    #pragma unroll
    for (int j = 0; j < PW; ++j) {
        ws[j] = (int)fminf(fmaxf(floorf((float)j * bsw) + sw, 0.0f), (float)W_FEAT);
        we[j] = (int)fminf(fmaxf(ceilf((float)(j + 1) * bsw) + sw, 0.0f), (float)W_FEAT);
    }
    float mx[PW];
    #pragma unroll
    for (int j = 0; j < PW; ++j) mx[j] = -1e30f;
    for (int y = hs; y < he; ++y) {
        const float* fr = feat + (size_t)c * P_FEAT + y * W_FEAT;
        #pragma unroll
        for (int j = 0; j < PW; ++j)
            for (int x = ws[j]; x < we[j]; ++x)
                mx[j] = fmaxf(mx[j], fr[x]);
    }
    const bool rowv = (he > hs);
    float* ob = out + (size_t)b * POOL_PER_BOX + (size_t)c * CELLS + i * PW;
    #pragma unroll
    for (int j = 0; j < PW; ++j)
        ob[j] = (rowv && (we[j] > ws[j])) ? mx[j] : 0.0f;
}

// ---------------------------------------------------------------------------
extern "C" void kernel_launch(void* const* d_in, const int* in_sizes, int n_in,
                              void* d_out, int out_size, void* d_ws, size_t ws_size,
                              hipStream_t stream) {
    const float* features = (const float*)d_in[0];   // (1,256,40,40)
    const float* rois     = (const float*)d_in[1];   // (32,5)
    const int*   hh_p     = (const int*)d_in[2];
    const int*   hw_p     = (const int*)d_in[3];

    float* out      = (float*)d_out;
    float* cat_out  = out + OUT_POOL_ELEMS;          // (288,5) tail of d_out
    float* ft       = (float*)d_ws;                  // transposed features

    const size_t ft_bytes = (size_t)C_FEAT * P_FEAT * sizeof(float);
    const int use_transpose = (ws_size >= ft_bytes + 64) ? 1 : 0;

    if (use_transpose) {
        // Single cooperative dispatch: no inter-launch gap (v8's ~10us loss).
        void* args[] = {(void*)&features, (void*)&rois, (void*)&hh_p,
                        (void*)&hw_p, (void*)&out, (void*)&ft};
        hipError_t e = hipLaunchCooperativeKernel((const void*)coop_v9,
                                                  dim3(CBLK), dim3(TPB),
                                                  args, 0, stream);
        if (e == hipSuccess) return;
        (void)hipGetLastError();                     // clear; fall back to v8
        hipLaunchKernelGGL(prep_kernel, dim3(N_TRANS_BLOCKS + 1), dim3(256), 0,
                           stream, features, rois, hh_p, hw_p, ft, cat_out, 1);
        hipLaunchKernelGGL(pool_v8, dim3(NBLK8), dim3(TPB), 0, stream,
                           ft, cat_out, out);
    } else {
        hipLaunchKernelGGL(prep_kernel, dim3(N_TRANS_BLOCKS + 1), dim3(256), 0,
                           stream, features, rois, hh_p, hw_p, ft, cat_out, 0);
        hipLaunchKernelGGL(roi_pool_kernel_nchw, dim3(PH * N_CAT), dim3(C_FEAT),
                           0, stream, features, cat_out, out);
    }
}

// Round 10
// 76.812 us; speedup vs baseline: 1.6559x; 1.6559x over previous
//
#include <hip/hip_runtime.h>
#include <math.h>

// Problem constants (from reference / setup_inputs)
#define N_ROIS   32
#define N_CAT    (N_ROIS * 9)      // 288 cat_rois rows
#define C_FEAT   256
#define H_FEAT   40
#define W_FEAT   40
#define P_FEAT   (H_FEAT * W_FEAT) // 1600 pixels
#define PH       7
#define PW       7
#define SCALE    0.0625f
#define MIN_SIZE 16.0f
#define CELLS    (PH * PW)                 // 49
#define POOL_PER_BOX (C_FEAT * CELLS)      // 12544
#define OUT_POOL_ELEMS ((size_t)N_CAT * POOL_PER_BOX)  // 3,612,672

// Fused-kernel geometry: block = (box, channel-quarter)
#define CH_G     64                         // channels per block
#define NCHG     4
#define NBLK     (N_CAT * NCHG)             // 1152 == 8 * 144 (XCD-bijective)
#define TPB      448                        // 64 ch x 7 pooled rows = 7 waves
#define WROWS    14                         // max window rows (bsh <= 2)
#define CST      21                         // ch-stride (odd -> compute reads
                                            // lane-stride 21: conflict-free)
#define YST      (CH_G * CST + 1)           // 1345
#define WIN_FLTS (13 * YST + 63 * CST + 20) // 18,828 floats = 75.3 KB (v7)
#define OBUF_FLTS (CH_G * CELLS)            // 3136 floats (overlays win)

// ---------------------------------------------------------------------------
// Staging helper: NQD is a COMPILE-TIME quad count so e%NQD / e/NQD are
// magic-mul const-divides; ch=(e/NQD)&63 and yy=(e/NQD)>>6 are bit ops.
// Lane pattern: NQD lanes share one (yy,ch) 16*NQD-byte contiguous run;
// runs are ch-consecutive (6400B apart) -> ~64/NQD runs x 1-2 lines per
// wave-instr. Only WH real rows and NQd real quads staged (the trim).
// ---------------------------------------------------------------------------
template <int NQD>
__device__ __forceinline__ void stage_win(float* __restrict__ win,
                                          const float* __restrict__ fbase,
                                          int WH, int q0, int ys, int tid) {
    const int n = WH * CH_G * NQD;                 // uniform trip bound
    for (int e = tid; e < n; e += TPB) {
        const int k  = e % NQD;                    // const-div (magic)
        const int m  = e / NQD;
        const int ch = m & 63;
        const int yy = m >> 6;
        const int gy = (ys + yy < H_FEAT - 1) ? (ys + yy) : (H_FEAT - 1);
        const int gq = (q0 + k < (W_FEAT / 4) - 1) ? (q0 + k) : (W_FEAT / 4) - 1;
        // clamped slots are never consumed (wave-uniform guards in compute)
        const float4 v = *(const float4*)(fbase + (size_t)ch * P_FEAT
                                          + gy * W_FEAT + gq * 4);
        float* wp = win + yy * YST + ch * CST + k * 4;
        wp[0] = v.x; wp[1] = v.y; wp[2] = v.z; wp[3] = v.w;
    }
}

// ---------------------------------------------------------------------------
// v10 = v7 (best measured: graded 78.1, kernel ~22us, PASSED) + trimmed
// staging. Transaction model (validated: v7 = 2000 lines/blk x 4.5 blk/CU
// x ~6cy = 22us): v7 staged the static 14-row x 5-quad worst case; the real
// window is WH~7-9 rows, NQd~3-4 quads. Trimming cuts stage lines
// ~1790 -> ~1030; total ~1230 lines/blk -> predicted ~14us.
// Everything else verbatim from v7: single plain launch (coop adds +23us
// fixed, 2nd launch adds ~10us gap - both measured), per-block geometry +
// lane-parallel IoU butterfly, wave-uniform <=3-read guarded compute,
// obuf overlay + dense float4 drain, XCD-bijective swizzle.
// ---------------------------------------------------------------------------
__global__ __launch_bounds__(TPB) void
fused_v10(const float* __restrict__ f,
          const float* __restrict__ rois,
          const int* __restrict__ hh_p,
          const int* __restrict__ hw_p,
          float* __restrict__ out) {
    __shared__ __align__(16) float win[WIN_FLTS];   // 75,312 B

    const int bid  = blockIdx.x;
    // XCD-bijective swizzle (1152 = 8*144); box's 4 ch-quarters adjacent in s
    const int s    = (bid & 7) * (NBLK / 8) + (bid >> 3);
    const int b    = s >> 2;            // box 0..287
    const int cg   = s & 3;             // channel quarter
    const int tid  = threadIdx.x;
    const int lane = tid & 63;

    // ---- box geometry (block-uniform result; verbatim v5-v7: PASSED) ----
    const int n  = b / 9;
    const int jj = b % 9;
    const float x1 = rois[n * 5 + 1], y1 = rois[n * 5 + 2];
    const float x2 = rois[n * 5 + 3], y2 = rois[n * 5 + 4];
    float bx1, by1, bx2, by2;

    if (jj == 0) {                      // parent roi row
        bx1 = x1; by1 = y1; bx2 = x2; by2 = y2;
    } else {
        const int j = jj - 1;
        const int m = (j < 4) ? j : j + 1;   // skip center of 3x3
        const int r  = m / 3;
        const int cc = m % 3;
        const float w = x2 - x1, h = y2 - y1;
        const float cx = x1 + w * ((float)cc - 0.5f);
        const float cy = y1 + h * ((float)r  - 0.5f);
        bx1 = cx - w * 0.25f;
        by1 = cy - h * 0.25f;
        bx2 = cx + w * 0.25f;
        by2 = cy + h * 0.25f;
        const float bw = bx2 - bx1 + 1.0f;
        const float bh = by2 - by1 + 1.0f;
        const float hh = (float)(*hh_p);
        const float hw = (float)(*hw_p);
        const bool invalid = (bx1 < 0.0f) || (by1 < 0.0f) ||
                             (bx2 >= hw) || (by2 >= hh) ||
                             (bw < MIN_SIZE) || (bh < MIN_SIZE);
        if (invalid) { bx1 = x1; by1 = y1; bx2 = x2; by2 = y2; }

        const float gw = bx2 - bx1 + 1.0f;
        const float gh = by2 - by1 + 1.0f;
        const float garea = gw * gh;
        const bool gdeg = (gw == 1.0f) && (gh == 1.0f);

        // ---- lane-parallel IoU: lane (a = lane&31) scores roi a ----
        const int a = lane & 31;
        const float ax1 = rois[a * 5 + 1], ay1 = rois[a * 5 + 2];
        const float ax2 = rois[a * 5 + 3], ay2 = rois[a * 5 + 4];
        const float aw = ax2 - ax1 + 1.0f, ah = ay2 - ay1 + 1.0f;
        const float iw = fmaxf(fminf(ax2, bx2) - fmaxf(ax1, bx1) + 1.0f, 0.0f);
        const float ih = fmaxf(fminf(ay2, by2) - fmaxf(ay1, by1) + 1.0f, 0.0f);
        const float inter = iw * ih;
        float ov = inter / (aw * ah + garea - inter);
        if (gdeg) ov = 0.0f;
        if (aw == 1.0f && ah == 1.0f) ov = -1.0f;
        int ai = a;
        // butterfly max + FIRST-argmax (tie -> smaller index == jnp.argmax)
        #pragma unroll
        for (int off = 32; off >= 1; off >>= 1) {
            const float o2 = __shfl_xor(ov, off);
            const int   a2 = __shfl_xor(ai, off);
            if (o2 > ov || (o2 == ov && a2 < ai)) { ov = o2; ai = a2; }
        }

        bool label = (ov >= 0.3f);
        const float w_cell = bx2 - bx1;
        const float h_cell = by2 - by1;
        const float rw = label ? (rois[ai * 5 + 3] - rois[ai * 5 + 1]) : 0.0f;
        const float rh = label ? (rois[ai * 5 + 4] - rois[ai * 5 + 2]) : 0.0f;
        label = label &&
                !(fmaxf(rw, rh) >= fmaxf(w_cell, h_cell)) &&
                !(fminf(rw, rh) < fminf(w_cell, h_cell) / 3.0f);
        if (label) {
            bx1 = rois[ai * 5 + 1]; by1 = rois[ai * 5 + 2];
            bx2 = rois[ai * 5 + 3]; by2 = rois[ai * 5 + 4];
        }
    }

    // cat_rois output row (one writer per box)
    if (cg == 0 && tid == 0) {
        float* row = out + OUT_POOL_ELEMS + (size_t)b * 5;
        row[0] = (jj == 0) ? rois[n * 5] : 0.0f;
        row[1] = bx1; row[2] = by1; row[3] = bx2; row[4] = by2;
    }

    // ---- pooling geometry (block-uniform -> SGPRs) ----
    // jnp.round = round-half-to-even = rintf (default rounding mode)
    const float sw = rintf(bx1 * SCALE);
    const float sh = rintf(by1 * SCALE);
    const float ew = rintf(bx2 * SCALE);
    const float eh = rintf(by2 * SCALE);
    const float bsh = fmaxf(eh - sh + 1.0f, 1.0f) * (1.0f / (float)PH);
    const float bsw = fmaxf(ew - sw + 1.0f, 1.0f) * (1.0f / (float)PW);

    const int cl = tid & 63;          // local channel 0..63 (compute phase)
    const int i  = tid >> 6;          // pooled row 0..6 (wave-uniform)

    const int hs = __builtin_amdgcn_readfirstlane(
        (int)fminf(fmaxf(floorf((float)i * bsh) + sh, 0.0f), (float)H_FEAT));
    const int he = __builtin_amdgcn_readfirstlane(
        (int)fminf(fmaxf(ceilf((float)(i + 1) * bsh) + sh, 0.0f), (float)H_FEAT));

    int ws[PW], we[PW];
    #pragma unroll
    for (int j = 0; j < PW; ++j) {
        ws[j] = __builtin_amdgcn_readfirstlane(
            (int)fminf(fmaxf(floorf((float)j * bsw) + sw, 0.0f), (float)W_FEAT));
        we[j] = __builtin_amdgcn_readfirstlane(
            (int)fminf(fmaxf(ceilf((float)(j + 1) * bsw) + sw, 0.0f), (float)W_FEAT));
    }
    const int xs = ws[0];                       // window col start (= clamp(sw))
    const int ys = __builtin_amdgcn_readfirstlane(
        (int)fminf(fmaxf(sh, 0.0f), (float)H_FEAT));  // window row start
    const int yend = __builtin_amdgcn_readfirstlane(
        (int)fminf(fmaxf(ceilf((float)PH * bsh) + sh, 0.0f), (float)H_FEAT));
    const int WH = yend - ys;                   // 0..14 actual window rows
    const int q0 = xs >> 2;                     // aligned quad base
    // quads actually USED: floats [0, we[6]-4*q0); guarded-out reads hit
    // stale LDS (never consumed), so NQd covers only used values.
    int XMAX = we[PW - 1] - 4 * q0;
    if (XMAX < 1) XMAX = 1;
    const int NQd = (XMAX + 3) >> 2;            // 1..5, block-uniform

    // bsw,bsh <= 2 (max roi 200px): WH<=14, we[6]-xs<=14, we[j]-ws[j]<=3.
    const bool narrow = (bsw <= 2.0f) && (bsh <= 2.0f);   // block-uniform
    const bool rowv = (he > hs);

    if (narrow) {
        // ---- trimmed stage: WH rows x NQd quads x 64 ch, NCHW -> LDS ----
        const float* fbase = f + (size_t)(cg * CH_G) * P_FEAT;
        switch (NQd) {                          // uniform branch
            case 1: stage_win<1>(win, fbase, WH, q0, ys, tid); break;
            case 2: stage_win<2>(win, fbase, WH, q0, ys, tid); break;
            case 3: stage_win<3>(win, fbase, WH, q0, ys, tid); break;
            case 4: stage_win<4>(win, fbase, WH, q0, ys, tid); break;
            default: stage_win<5>(win, fbase, WH, q0, ys, tid); break;
        }
        __syncthreads();

        // ---- compute: per cell <=3 batched ds_reads + uniform guards ----
        float mx[PW];
        #pragma unroll
        for (int j = 0; j < PW; ++j) mx[j] = -1e30f;

        int off[PW], nj[PW];
        #pragma unroll
        for (int j = 0; j < PW; ++j) {
            off[j] = ws[j] - 4 * q0;         // 0..17 (SGPR)
            nj[j]  = we[j] - ws[j];          // 0..3  (SGPR)
        }
        for (int y = hs; y < he; ++y) {
            const float* wr = win + (y - ys) * YST + cl * CST;
            #pragma unroll
            for (int j = 0; j < PW; ++j) {
                // 3 independent reads; over-reads (beyond NQd*4) hit stale
                // LDS inside the allocation and are guarded-unused.
                const float* p0 = wr + off[j];
                const float d0 = p0[0];
                const float d1 = p0[1];
                const float d2 = p0[2];
                if (nj[j] > 0) mx[j] = fmaxf(mx[j], d0);   // uniform guards
                if (nj[j] > 1) mx[j] = fmaxf(mx[j], d1);
                if (nj[j] > 2) mx[j] = fmaxf(mx[j], d2);
            }
        }
        __syncthreads();    // all win reads done -> safe to overlay obuf

        // ---- obuf (overlays win): stride 49 (odd: conflict-free) ----
        float* orow = win + cl * CELLS + i * PW;
        #pragma unroll
        for (int j = 0; j < PW; ++j)
            orow[j] = (rowv && (nj[j] > 0)) ? mx[j] : 0.0f;
        __syncthreads();

        // ---- dense drain: 784 float4 -> contiguous out slice (196 lines) ----
        const float4* src = (const float4*)win;
        float4* dst = (float4*)(out + (size_t)b * POOL_PER_BOX
                                    + (size_t)cg * OBUF_FLTS);
        dst[tid] = src[tid];
        const int e2 = tid + TPB;
        if (e2 < OBUF_FLTS / 4) dst[e2] = src[e2];
    } else {
        // general fallback (not taken for this data): direct NCHW reads,
        // direct scatter stores (correct, slow)
        const int c = cg * CH_G + cl;
        float mx[PW];
        #pragma unroll
        for (int j = 0; j < PW; ++j) mx[j] = -1e30f;
        for (int y = hs; y < he; ++y) {
            const float* fr = f + (size_t)c * P_FEAT + y * W_FEAT;
            #pragma unroll
            for (int j = 0; j < PW; ++j)
                for (int x = ws[j]; x < we[j]; ++x)
                    mx[j] = fmaxf(mx[j], fr[x]);
        }
        float* ob = out + (size_t)b * POOL_PER_BOX + (size_t)c * CELLS + i * PW;
        #pragma unroll
        for (int j = 0; j < PW; ++j)
            ob[j] = (rowv && (we[j] > ws[j])) ? mx[j] : 0.0f;
    }
}

// ---------------------------------------------------------------------------
extern "C" void kernel_launch(void* const* d_in, const int* in_sizes, int n_in,
                              void* d_out, int out_size, void* d_ws, size_t ws_size,
                              hipStream_t stream) {
    const float* features = (const float*)d_in[0];   // (1,256,40,40)
    const float* rois     = (const float*)d_in[1];   // (32,5)
    const int*   hh_p     = (const int*)d_in[2];
    const int*   hw_p     = (const int*)d_in[3];

    float* out = (float*)d_out;
    (void)d_ws; (void)ws_size; (void)in_sizes; (void)n_in; (void)out_size;

    // ONE plain launch (measured: coop adds ~23us fixed, a 2nd dependent
    // launch adds ~10us gap; graded = ~56us fixed + kernel).
    hipLaunchKernelGGL(fused_v10, dim3(NBLK), dim3(TPB), 0, stream,
                       features, rois, hh_p, hw_p, out);
}